// Round 1
// baseline (2376.156 us; speedup 1.0000x reference)
//
#include <hip/hip_runtime.h>
#include <hip/hip_bf16.h>

#define WIDTH 512
#define HDIM 1024
#define NNODES 200000
#define NGRAPHS 2000

typedef __bf16 bf16_t;
typedef __bf16 bf16x4 __attribute__((ext_vector_type(4)));
typedef __bf16 bf16x8 __attribute__((ext_vector_type(8)));
typedef float f32x4 __attribute__((ext_vector_type(4)));

__device__ __forceinline__ void async_copy16(const void* g, void* l) {
    __builtin_amdgcn_global_load_lds(
        (const __attribute__((address_space(1))) unsigned int*)g,
        (__attribute__((address_space(3))) unsigned int*)l,
        16, 0, 0);
}

__device__ __forceinline__ float gelu_exact(float v) {
    return 0.5f * v * (1.0f + erff(v * 0.70710678118654752f));
}

// Retile fp32 weight [K][C] -> bf16 [K/32][C][32] (n-major, k-contiguous within tile)
__global__ void __launch_bounds__(256) k_tile(const float* __restrict__ src,
                                              bf16_t* __restrict__ dst,
                                              int K, int C) {
    int tid = blockIdx.x * 256 + threadIdx.x;
    int total = K * C;
    if (tid >= total) return;
    int kin = tid & 31;
    int rest = tid >> 5;
    int n = rest % C;
    int kt = rest / C;
    dst[tid] = (bf16_t)src[(size_t)(kt * 32 + kin) * C + n];
}

// pre GEMM (x @ pre_w + pre_b) fused with LayerNorm -> xx bf16 [N][512]
// tile: 32 rows x 512 cols, 4 waves (each wave 32x128), BK=32, K=512
__global__ void __launch_bounds__(256) k_pre(const float* __restrict__ x,
                                             const float* __restrict__ pre_b,
                                             const bf16_t* __restrict__ preT,
                                             bf16_t* __restrict__ xx) {
    __shared__ bf16_t lA[32 * 32];
    __shared__ bf16_t lB[512 * 32];
    __shared__ float redS[4 * 32];
    __shared__ float redQ[4 * 32];
    __shared__ float muS[32];
    __shared__ float rsS[32];

    const int tid = threadIdx.x;
    const int wave = tid >> 6;
    const int lane = tid & 63;
    const int l15 = lane & 15;
    const int l4 = lane >> 4;
    const int rows0 = blockIdx.x * 32;

    f32x4 acc[2][8];
    const f32x4 z = {0.f, 0.f, 0.f, 0.f};
#pragma unroll
    for (int i = 0; i < 2; ++i)
#pragma unroll
        for (int j = 0; j < 8; ++j) acc[i][j] = z;

    const int ar = tid >> 3;         // 0..31 (row)
    const int ac = (tid & 7) << 2;   // 0,4,..,28 (k within tile)

    for (int kt = 0; kt < 16; ++kt) {
        // A stage: 32x32 fp32 -> bf16 (manual cast)
        {
            const float4 f = *(const float4*)(x + (size_t)(rows0 + ar) * 512 + kt * 32 + ac);
            bf16x4 p;
            p.x = (bf16_t)f.x; p.y = (bf16_t)f.y; p.z = (bf16_t)f.z; p.w = (bf16_t)f.w;
            *(bf16x4*)(lA + ar * 32 + ac) = p;
        }
        // B stage: 512x32 bf16 contiguous from tiled weight, 8 chunks/wave
        {
            const char* bsrc = (const char*)preT + (size_t)kt * 32768 + (size_t)lane * 16;
            char* ldst = (char*)lB + wave * 8192;
#pragma unroll
            for (int i = 0; i < 8; ++i)
                async_copy16(bsrc + (wave * 8 + i) * 1024, ldst + i * 1024);
        }
        __syncthreads();
        bf16x8 af[2];
        af[0] = *(const bf16x8*)(lA + l15 * 32 + l4 * 8);
        af[1] = *(const bf16x8*)(lA + (16 + l15) * 32 + l4 * 8);
#pragma unroll
        for (int nf = 0; nf < 8; ++nf) {
            bf16x8 bfr = *(const bf16x8*)(lB + (wave * 128 + nf * 16 + l15) * 32 + l4 * 8);
            acc[0][nf] = __builtin_amdgcn_mfma_f32_16x16x32_bf16(af[0], bfr, acc[0][nf], 0, 0, 0);
            acc[1][nf] = __builtin_amdgcn_mfma_f32_16x16x32_bf16(af[1], bfr, acc[1][nf], 0, 0, 0);
        }
        __syncthreads();
    }

    // epilogue: +bias, LayerNorm over 512 cols, store bf16
    float bias[8];
#pragma unroll
    for (int nf = 0; nf < 8; ++nf) bias[nf] = pre_b[wave * 128 + nf * 16 + l15];
#pragma unroll
    for (int mf = 0; mf < 2; ++mf)
#pragma unroll
        for (int nf = 0; nf < 8; ++nf)
#pragma unroll
            for (int r = 0; r < 4; ++r) acc[mf][nf][r] += bias[nf];

    float s[2][4], q[2][4];
#pragma unroll
    for (int mf = 0; mf < 2; ++mf)
#pragma unroll
        for (int r = 0; r < 4; ++r) {
            float ss = 0.f, qq = 0.f;
#pragma unroll
            for (int nf = 0; nf < 8; ++nf) {
                float v = acc[mf][nf][r];
                ss += v; qq += v * v;
            }
            s[mf][r] = ss; q[mf][r] = qq;
        }
#pragma unroll
    for (int m = 1; m <= 8; m <<= 1) {
#pragma unroll
        for (int mf = 0; mf < 2; ++mf)
#pragma unroll
            for (int r = 0; r < 4; ++r) {
                s[mf][r] += __shfl_xor(s[mf][r], m, 16);
                q[mf][r] += __shfl_xor(q[mf][r], m, 16);
            }
    }
    if (l15 == 0) {
#pragma unroll
        for (int mf = 0; mf < 2; ++mf)
#pragma unroll
            for (int r = 0; r < 4; ++r) {
                int row = mf * 16 + l4 * 4 + r;
                redS[wave * 32 + row] = s[mf][r];
                redQ[wave * 32 + row] = q[mf][r];
            }
    }
    __syncthreads();
    if (tid < 32) {
        float S = redS[tid] + redS[32 + tid] + redS[64 + tid] + redS[96 + tid];
        float Q = redQ[tid] + redQ[32 + tid] + redQ[64 + tid] + redQ[96 + tid];
        float mu = S * (1.0f / 512.0f);
        float var = Q * (1.0f / 512.0f) - mu * mu;
        muS[tid] = mu;
        rsS[tid] = rsqrtf(var + 1e-5f);
    }
    __syncthreads();
#pragma unroll
    for (int mf = 0; mf < 2; ++mf)
#pragma unroll
        for (int r = 0; r < 4; ++r) {
            int row = mf * 16 + l4 * 4 + r;
            float mu = muS[row], rs = rsS[row];
            size_t base = (size_t)(rows0 + row) * 512;
#pragma unroll
            for (int nf = 0; nf < 8; ++nf) {
                float v = (acc[mf][nf][r] - mu) * rs;
                xx[base + wave * 128 + nf * 16 + l15] = (bf16_t)v;
            }
        }
}

// segment sum pooled[g] = sum xx rows in [start,end) (batch sorted)
__global__ void __launch_bounds__(256) k_pool(const bf16_t* __restrict__ xx,
                                              const int* __restrict__ batch,
                                              float* __restrict__ pooled) {
    int g = blockIdx.x;
    int tid = threadIdx.x;
    int start, end;
    {
        int l = 0, h = NNODES;
        while (l < h) { int m = (l + h) >> 1; if (batch[m] < g) l = m + 1; else h = m; }
        start = l;
    }
    {
        int l = start, h = NNODES;
        while (l < h) { int m = (l + h) >> 1; if (batch[m] < g + 1) l = m + 1; else h = m; }
        end = l;
    }
    float a0 = 0.f, a1 = 0.f;
    const unsigned int* base = (const unsigned int*)xx;
    for (int r = start; r < end; ++r) {
        unsigned int u = base[(size_t)r * 256 + tid];
        union { unsigned int i; float f; } c0, c1;
        c0.i = u << 16;
        c1.i = u & 0xffff0000u;
        a0 += c0.f;
        a1 += c1.f;
    }
    ((float2*)(pooled + (size_t)g * 512))[tid] = make_float2(a0, a1);
}

// msg = gelu(pooled @ msg_w + msg_b) * exp(zero) -> bf16 [G][1024]
// block: 16 graphs x 256 cols, pooled tile staged in LDS
__global__ void __launch_bounds__(256) k_msg(const float* __restrict__ pooled,
                                             const float* __restrict__ msg_w,
                                             const float* __restrict__ msg_b,
                                             const float* __restrict__ zero,
                                             bf16_t* __restrict__ msgb) {
    __shared__ float lp[16 * 512];
    int tid = threadIdx.x;
    int g0 = blockIdx.y * 16;
    int j = blockIdx.x * 256 + tid;
    for (int idx = tid; idx < 8192; idx += 256) lp[idx] = pooled[(size_t)g0 * 512 + idx];
    __syncthreads();
    float a[16];
    float bj = msg_b[j];
#pragma unroll
    for (int i = 0; i < 16; ++i) a[i] = bj;
    for (int k = 0; k < 512; ++k) {
        float w = msg_w[(size_t)k * HDIM + j];
#pragma unroll
        for (int i = 0; i < 16; ++i) a[i] = fmaf(lp[i * 512 + k], w, a[i]);
    }
    float ez = expf(zero[0]);
#pragma unroll
    for (int i = 0; i < 16; ++i) {
        float v = gelu_exact(a[i]) * ez;
        msgb[(size_t)(g0 + i) * HDIM + j] = (bf16_t)v;
    }
}

// mem GEMM: t = gelu(xx @ mem_w + mem_b) + msg[batch]  -> bf16 [N][1024]
// 128x128 tile, 4 waves (2x2, each 64x64), BK=32, K=512
__global__ void __launch_bounds__(256) k_mem(const bf16_t* __restrict__ xx,
                                             const bf16_t* __restrict__ memT,
                                             const float* __restrict__ mem_b,
                                             const bf16_t* __restrict__ msgb,
                                             const int* __restrict__ batch,
                                             bf16_t* __restrict__ t) {
    __shared__ bf16_t lA[128 * 32];
    __shared__ bf16_t lB[128 * 32];
    __shared__ int gidx[128];
    const int tid = threadIdx.x;
    const int wave = tid >> 6;
    const int lane = tid & 63;
    const int l15 = lane & 15;
    const int l4 = lane >> 4;
    const int wm = wave >> 1;
    const int wn = wave & 1;
    const int rows0 = blockIdx.y * 128;
    const int nb0 = blockIdx.x * 128;

    if (tid < 128) {
        int rg = rows0 + tid;
        gidx[tid] = batch[rg < NNODES ? rg : (NNODES - 1)];
    }

    f32x4 acc[4][4];
    const f32x4 z = {0.f, 0.f, 0.f, 0.f};
#pragma unroll
    for (int i = 0; i < 4; ++i)
#pragma unroll
        for (int j = 0; j < 4; ++j) acc[i][j] = z;

    const int arow = lane >> 2;
    const int akc = lane & 3;

    for (int kt = 0; kt < 16; ++kt) {
#pragma unroll
        for (int i = 0; i < 2; ++i) {
            int c = wave + i * 4;
            int row = rows0 + c * 16 + arow;
            if (row > NNODES - 1) row = NNODES - 1;
            const char* ga = (const char*)xx + (size_t)row * 1024 + kt * 64 + akc * 16;
            async_copy16(ga, (char*)lA + c * 1024);
        }
        {
            const char* gb = (const char*)memT + ((size_t)kt * HDIM + nb0) * 64 + (size_t)lane * 16;
#pragma unroll
            for (int i = 0; i < 2; ++i) {
                int c = wave + i * 4;
                async_copy16(gb + c * 1024, (char*)lB + c * 1024);
            }
        }
        __syncthreads();
        bf16x8 af[4], bfr[4];
#pragma unroll
        for (int mf = 0; mf < 4; ++mf)
            af[mf] = *(const bf16x8*)(lA + (wm * 64 + mf * 16 + l15) * 32 + l4 * 8);
#pragma unroll
        for (int nf = 0; nf < 4; ++nf)
            bfr[nf] = *(const bf16x8*)(lB + (wn * 64 + nf * 16 + l15) * 32 + l4 * 8);
#pragma unroll
        for (int mf = 0; mf < 4; ++mf)
#pragma unroll
            for (int nf = 0; nf < 4; ++nf)
                acc[mf][nf] = __builtin_amdgcn_mfma_f32_16x16x32_bf16(af[mf], bfr[nf], acc[mf][nf], 0, 0, 0);
        __syncthreads();
    }

    float bias[4];
    int colg[4];
#pragma unroll
    for (int nf = 0; nf < 4; ++nf) {
        colg[nf] = nb0 + wn * 64 + nf * 16 + l15;
        bias[nf] = mem_b[colg[nf]];
    }
#pragma unroll
    for (int mf = 0; mf < 4; ++mf)
#pragma unroll
        for (int r = 0; r < 4; ++r) {
            int row = wm * 64 + mf * 16 + l4 * 4 + r;
            int rowg = rows0 + row;
            if (rowg < NNODES) {
                const bf16_t* mrow = msgb + (size_t)gidx[row] * HDIM;
                bf16_t* trow = t + (size_t)rowg * HDIM;
#pragma unroll
                for (int nf = 0; nf < 4; ++nf) {
                    float v = acc[mf][nf][r] + bias[nf];
                    v = gelu_exact(v);
                    v += (float)mrow[colg[nf]];
                    trow[colg[nf]] = (bf16_t)v;
                }
            }
        }
}

// post GEMM: out_xx = t @ post_w + post_b; out0 = x + out_xx; out1 = out_xx
// 128x128 tile, BK=32, K=1024
__global__ void __launch_bounds__(256) k_post(const bf16_t* __restrict__ t,
                                              const bf16_t* __restrict__ postT,
                                              const float* __restrict__ post_b,
                                              const float* __restrict__ x,
                                              float* __restrict__ out) {
    __shared__ bf16_t lA[128 * 32];
    __shared__ bf16_t lB[128 * 32];
    const int tid = threadIdx.x;
    const int wave = tid >> 6;
    const int lane = tid & 63;
    const int l15 = lane & 15;
    const int l4 = lane >> 4;
    const int wm = wave >> 1;
    const int wn = wave & 1;
    const int rows0 = blockIdx.y * 128;
    const int nb0 = blockIdx.x * 128;

    f32x4 acc[4][4];
    const f32x4 z = {0.f, 0.f, 0.f, 0.f};
#pragma unroll
    for (int i = 0; i < 4; ++i)
#pragma unroll
        for (int j = 0; j < 4; ++j) acc[i][j] = z;

    const int arow = lane >> 2;
    const int akc = lane & 3;

    for (int kt = 0; kt < 32; ++kt) {
#pragma unroll
        for (int i = 0; i < 2; ++i) {
            int c = wave + i * 4;
            int row = rows0 + c * 16 + arow;
            if (row > NNODES - 1) row = NNODES - 1;
            const char* ga = (const char*)t + (size_t)row * 2048 + kt * 64 + akc * 16;
            async_copy16(ga, (char*)lA + c * 1024);
        }
        {
            const char* gb = (const char*)postT + ((size_t)kt * 512 + nb0) * 64 + (size_t)lane * 16;
#pragma unroll
            for (int i = 0; i < 2; ++i) {
                int c = wave + i * 4;
                async_copy16(gb + c * 1024, (char*)lB + c * 1024);
            }
        }
        __syncthreads();
        bf16x8 af[4], bfr[4];
#pragma unroll
        for (int mf = 0; mf < 4; ++mf)
            af[mf] = *(const bf16x8*)(lA + (wm * 64 + mf * 16 + l15) * 32 + l4 * 8);
#pragma unroll
        for (int nf = 0; nf < 4; ++nf)
            bfr[nf] = *(const bf16x8*)(lB + (wn * 64 + nf * 16 + l15) * 32 + l4 * 8);
#pragma unroll
        for (int mf = 0; mf < 4; ++mf)
#pragma unroll
            for (int nf = 0; nf < 4; ++nf)
                acc[mf][nf] = __builtin_amdgcn_mfma_f32_16x16x32_bf16(af[mf], bfr[nf], acc[mf][nf], 0, 0, 0);
        __syncthreads();
    }

    float bias[4];
    int colg[4];
#pragma unroll
    for (int nf = 0; nf < 4; ++nf) {
        colg[nf] = nb0 + wn * 64 + nf * 16 + l15;
        bias[nf] = post_b[colg[nf]];
    }
    const size_t NW = (size_t)NNODES * 512;
#pragma unroll
    for (int mf = 0; mf < 4; ++mf)
#pragma unroll
        for (int r = 0; r < 4; ++r) {
            int row = wm * 64 + mf * 16 + l4 * 4 + r;
            int rowg = rows0 + row;
            if (rowg < NNODES) {
#pragma unroll
                for (int nf = 0; nf < 4; ++nf) {
                    float v = acc[mf][nf][r] + bias[nf];
                    size_t o = (size_t)rowg * 512 + colg[nf];
                    out[o] = x[o] + v;
                    out[NW + o] = v;
                }
            }
        }
}

extern "C" void kernel_launch(void* const* d_in, const int* in_sizes, int n_in,
                              void* d_out, int out_size, void* d_ws, size_t ws_size,
                              hipStream_t stream) {
    const float* x      = (const float*)d_in[0];
    const int*   batch  = (const int*)d_in[1];
    const float* pre_w  = (const float*)d_in[2];
    const float* pre_b  = (const float*)d_in[3];
    const float* mem_w  = (const float*)d_in[4];
    const float* mem_b  = (const float*)d_in[5];
    const float* msg_w  = (const float*)d_in[6];
    const float* msg_b  = (const float*)d_in[7];
    const float* post_w = (const float*)d_in[8];
    const float* post_b = (const float*)d_in[9];
    const float* zero   = (const float*)d_in[10];
    float* out = (float*)d_out;

    char* ws = (char*)d_ws;
    bf16_t* xx     = (bf16_t*)(ws);                    // 204,800,000 B
    bf16_t* t      = (bf16_t*)(ws + 204800000);        // 409,600,000 B
    float*  pooled = (float*)(ws + 614400000);         //   4,096,000 B
    bf16_t* msgb   = (bf16_t*)(ws + 618496000);        //   4,096,000 B
    bf16_t* preT   = (bf16_t*)(ws + 622592000);        //     524,288 B
    bf16_t* memT   = (bf16_t*)(ws + 623116288);        //   1,048,576 B
    bf16_t* postT  = (bf16_t*)(ws + 624164864);        //   1,048,576 B

    k_tile<<<1024, 256, 0, stream>>>(pre_w, preT, 512, 512);
    k_tile<<<2048, 256, 0, stream>>>(mem_w, memT, 512, 1024);
    k_tile<<<2048, 256, 0, stream>>>(post_w, postT, 1024, 512);
    k_pre<<<6250, 256, 0, stream>>>(x, pre_b, preT, xx);
    k_pool<<<NGRAPHS, 256, 0, stream>>>(xx, batch, pooled);
    k_msg<<<dim3(4, 125), 256, 0, stream>>>(pooled, msg_w, msg_b, zero, msgb);
    k_mem<<<dim3(8, 1563), 256, 0, stream>>>(xx, memT, mem_b, msgb, batch, t);
    k_post<<<dim3(4, 1563), 256, 0, stream>>>(t, postT, post_b, x, out);
}